// Round 3
// baseline (254.828 us; speedup 1.0000x reference)
//
#include <hip/hip_runtime.h>
#include <math.h>

#define EPSF   1e-6f
#define SCALE  0.125f          // 1/sqrt(D), D=64
#define NEG_HUGE -3.402823466e38f

// p_k_i LDS layout: [4 kq blocks][1024 t][4], block stride skewed to 4104 floats
// (4104 % 32 == 8) so the 4 per-wave phase-B read addresses hit 4 disjoint
// 4-bank groups (banks {0,8,16,24}+) -> conflict-free ds_read_b128.
#define PW_STRIDE 4104

__device__ __forceinline__ float rs_nr(float x) {
    float r = rsqrtf(x);
    return r * (1.5f - 0.5f * x * r * r);   // one Newton step -> ~f32 accurate
}

__device__ __forceinline__ float dot4(float4 a, float4 b) {
    return fmaf(a.x, b.x, fmaf(a.y, b.y, fmaf(a.z, b.z, a.w * b.w)));
}

// Per-token epilogue of phase A: returns scores_t; leaves exp'd (unnormalized)
// K-softmax numerators in sk[16] and their sum in *se.
__device__ __forceinline__ float finish_token(
    float sz, float szz, float sa, float saa, float da,
    const float* dk, const float* s_sGP, const float* s_BP,
    float sG2Q, float TQc, float* sk, float* se)
{
    // LN stats for zn (z) and k_ (z+alphas)
    float m   = sz  * (1.f / 64.f);
    float var = szz * (1.f / 64.f) - m * m;
    float rs  = rs_nr(var + EPSF);
    float ma   = sa  * (1.f / 64.f);
    float vara = saa * (1.f / 64.f) - ma * ma;
    float rsa  = rs_nr(vara + EPSF);

    // scores_t (folded dense + LN): rsa*(u.G2Q - ma*sum(G2Q)) + (b2.q'' + Wb.q)
    float st = (rsa * (da - ma * sG2Q) + TQc) * SCALE;

    // scores_k -> exp(sk - max), keep in registers
    float mx = NEG_HUGE;
#pragma unroll
    for (int k = 0; k < 16; ++k) {
        float s = (rs * (dk[k] - m * s_sGP[k]) + s_BP[k]) * SCALE;
        sk[k] = s;
        mx = fmaxf(mx, s);
    }
    float s0 = 0.f;
#pragma unroll
    for (int k = 0; k < 16; ++k) { sk[k] = __expf(sk[k] - mx); s0 += sk[k]; }
    *se = s0;
    return st;
}

extern "C" __global__ __launch_bounds__(512, 4)
void disent_encoder_kernel(const float* __restrict__ z,
                           const float* __restrict__ proto,
                           const float* __restrict__ alphas,
                           const float* __restrict__ b_bias,
                           const float* __restrict__ W,
                           const float* __restrict__ Wb,
                           const float* __restrict__ lng,
                           const float* __restrict__ lnb,
                           const float* __restrict__ beta_seq,
                           float* __restrict__ out)
{
    const int b    = blockIdx.x;        // batch index, grid = 512
    const int tid  = threadIdx.x;       // 512 threads = 8 waves
    const int lane = tid & 63;
    const int wid  = tid >> 6;

    __shared__ __align__(16) float s_pw[4 * PW_STRIDE];  // p_k_i*p_i; aliased as phase-B partials
    __shared__ __align__(16) float s_GP[16 * 64];        // g0 * pn_k
    __shared__ __align__(16) float s_G2Q[64];            // g2 * q''
    __shared__ float s_sGP[16];
    __shared__ float s_BP[16];
    __shared__ float s_red[12];
    __shared__ float s_c[2];            // {sum(G2Q), b2.q'' + Wb.q}

    const float* zb = z + (size_t)b * 1024 * 64;

    // ---------------- prologue ----------------
    if (wid == 0) {
        // q = LN(alphas[-1] + z[:, -1] + b_bias); q'' = q + W@q; G2Q = g2*q''
        int d = lane;
        float a = alphas[1023 * 64 + d] + zb[1023 * 64 + d] + b_bias[d];
        float s1 = a, s2 = a * a;
#pragma unroll
        for (int off = 32; off >= 1; off >>= 1) {
            s1 += __shfl_xor(s1, off);
            s2 += __shfl_xor(s2, off);
        }
        float m  = s1 * (1.f / 64.f);
        float v  = s2 * (1.f / 64.f) - m * m;
        float rs = rs_nr(v + EPSF);
        float qd = fmaf((a - m) * rs, lng[3*64 + d], lnb[3*64 + d]);
        // W@q via shuffle broadcast: lane d dots row d of W with q
        float s = 0.f;
#pragma unroll 4
        for (int eq = 0; eq < 16; ++eq) {
            float4 w4 = *(const float4*)&W[d*64 + eq*4];
            s = fmaf(w4.x, __shfl(qd, 4*eq+0),
                fmaf(w4.y, __shfl(qd, 4*eq+1),
                fmaf(w4.z, __shfl(qd, 4*eq+2),
                fmaf(w4.w, __shfl(qd, 4*eq+3), s))));
        }
        float qpp  = qd + s;
        float G2Qd = lng[2*64 + d] * qpp;
        s_G2Q[d] = G2Qd;
        float r1 = G2Qd;                                   // -> sum(G2Q)
        float r2 = fmaf(lnb[2*64 + d], qpp, Wb[d] * qd);   // -> b2.q'' + Wb.q
#pragma unroll
        for (int off = 32; off >= 1; off >>= 1) {
            r1 += __shfl_xor(r1, off);
            r2 += __shfl_xor(r2, off);
        }
        if (d == 0) { s_c[0] = r1; s_c[1] = r2; }
    } else if (wid == 1 && lane < 16) {
        // pn = LN(prototypes_k); GP = g0*pn; sGP = sum(GP); BP = b0.pn
        int k = lane;
        float s1 = 0.f, s2 = 0.f;
#pragma unroll 4
        for (int qd = 0; qd < 16; ++qd) {
            float4 p = *(const float4*)&proto[k*64 + qd*4];
            s1 += (p.x + p.y) + (p.z + p.w);
            s2 += dot4(p, p);
        }
        float m  = s1 * (1.f / 64.f);
        float v  = s2 * (1.f / 64.f) - m * m;
        float rs = rs_nr(v + EPSF);
        float sgp = 0.f, bp = 0.f;
        for (int d2 = 0; d2 < 64; ++d2) {
            float pn = fmaf((proto[k*64 + d2] - m) * rs, lng[64 + d2], lnb[64 + d2]);
            float gp = lng[d2] * pn;
            s_GP[k*64 + d2] = gp;
            sgp += gp;
            bp = fmaf(lnb[d2], pn, bp);
        }
        s_sGP[k] = sgp;
        s_BP[k]  = bp;
    }
    __syncthreads();

    const float sG2Q = s_c[0];
    const float TQc  = s_c[1];

    // ---------------- phase A: per-token scores (2 tokens/thread) ----------------
    float st0, st1, se0, se1;
    float sk0[16], sk1[16];
    {
        const int t0 = tid;                 // tokens tid and tid+512
        const float4* zp[2] = { (const float4*)(zb + (size_t)t0 * 64),
                                (const float4*)(zb + (size_t)(t0 + 512) * 64) };
        const float4* ap[2] = { (const float4*)(alphas + (size_t)t0 * 64),
                                (const float4*)(alphas + (size_t)(t0 + 512) * 64) };
        float dk[2][16];
#pragma unroll
        for (int k = 0; k < 16; ++k) { dk[0][k] = 0.f; dk[1][k] = 0.f; }
        float sz[2]  = {0.f, 0.f}, szz[2] = {0.f, 0.f};
        float sa[2]  = {0.f, 0.f}, saa[2] = {0.f, 0.f}, da[2] = {0.f, 0.f};

#pragma unroll 4
        for (int qd = 0; qd < 16; ++qd) {
            float4 gq = *(const float4*)&s_G2Q[qd*4];
            float4 zq[2], aq[2];
#pragma unroll
            for (int j = 0; j < 2; ++j) { zq[j] = zp[j][qd]; aq[j] = ap[j][qd]; }
#pragma unroll
            for (int j = 0; j < 2; ++j) {
                float ux = zq[j].x + aq[j].x, uy = zq[j].y + aq[j].y;
                float uz = zq[j].z + aq[j].z, uw = zq[j].w + aq[j].w;
                sz[j]  += (zq[j].x + zq[j].y) + (zq[j].z + zq[j].w);
                szz[j]  = fmaf(zq[j].x, zq[j].x, fmaf(zq[j].y, zq[j].y,
                          fmaf(zq[j].z, zq[j].z, fmaf(zq[j].w, zq[j].w, szz[j]))));
                sa[j]  += (ux + uy) + (uz + uw);
                saa[j]  = fmaf(ux, ux, fmaf(uy, uy, fmaf(uz, uz, fmaf(uw, uw, saa[j]))));
                da[j]   = fmaf(ux, gq.x, fmaf(uy, gq.y, fmaf(uz, gq.z, fmaf(uw, gq.w, da[j]))));
            }
#pragma unroll
            for (int k = 0; k < 16; ++k) {
                float4 g = *(const float4*)&s_GP[k*64 + qd*4];   // wave-uniform broadcast
#pragma unroll
                for (int j = 0; j < 2; ++j)
                    dk[j][k] = fmaf(zq[j].x, g.x, fmaf(zq[j].y, g.y,
                               fmaf(zq[j].z, g.z, fmaf(zq[j].w, g.w, dk[j][k]))));
            }
        }
        st0 = finish_token(sz[0], szz[0], sa[0], saa[0], da[0], dk[0],
                           s_sGP, s_BP, sG2Q, TQc, sk0, &se0);
        st1 = finish_token(sz[1], szz[1], sa[1], saa[1], da[1], dk[1],
                           s_sGP, s_BP, sG2Q, TQc, sk1, &se1);
    }

    // ---------------- softmax over T (scores & K-numerators stay in registers) ---
    float lm = fmaxf(st0, st1);
#pragma unroll
    for (int off = 32; off >= 1; off >>= 1) lm = fmaxf(lm, __shfl_xor(lm, off));
    if (lane == 0) s_red[wid] = lm;
    __syncthreads();
    if (tid == 0) {
        float m0 = s_red[0];
#pragma unroll
        for (int w = 1; w < 8; ++w) m0 = fmaxf(m0, s_red[w]);
        s_red[8] = m0;
    }
    __syncthreads();
    float M  = s_red[8];
    float e0 = __expf(st0 - M), e1 = __expf(st1 - M);
    float ls = e0 + e1;
#pragma unroll
    for (int off = 32; off >= 1; off >>= 1) ls += __shfl_xor(ls, off);
    if (lane == 0) s_red[wid] = ls;
    __syncthreads();
    if (tid == 0) {
        float s0 = 0.f;
#pragma unroll
        for (int w = 0; w < 8; ++w) s0 += s_red[w];
        s_red[9] = 1.f / s0;
    }
    __syncthreads();
    float invZ = s_red[9];

    // Write fully-scaled weights w[t,k] = p_k_i[t,k] * p_i[t] to LDS (once).
    {
        float c0 = (e0 * invZ) / se0;
        float c1 = (e1 * invZ) / se1;
        const int t0 = tid;
#pragma unroll
        for (int kq = 0; kq < 4; ++kq) {
            float4 w0 = make_float4(sk0[4*kq+0]*c0, sk0[4*kq+1]*c0,
                                    sk0[4*kq+2]*c0, sk0[4*kq+3]*c0);
            float4 w1 = make_float4(sk1[4*kq+0]*c1, sk1[4*kq+1]*c1,
                                    sk1[4*kq+2]*c1, sk1[4*kq+3]*c1);
            *(float4*)&s_pw[kq*PW_STRIDE + t0*4]         = w0;   // lane-consecutive 16B
            *(float4*)&s_pw[kq*PW_STRIDE + (t0 + 512)*4] = w1;
        }
    }
    __syncthreads();

    // ---------------- phase B: out[k][d] = sum_t w[t,k]*z[t,d] ----------------
    const int kq = lane >> 4;     // 0..3  -> k quad
    const int dq = lane & 15;     // 0..15 -> d quad
    float acc[4][4];
#pragma unroll
    for (int i = 0; i < 4; ++i)
#pragma unroll
        for (int j = 0; j < 4; ++j) acc[i][j] = 0.f;

    const int tb = wid * 128;     // each of 8 waves owns 128 tokens
#pragma unroll 4
    for (int tt = 0; tt < 128; ++tt) {
        int t = tb + tt;
        float4 zq = *(const float4*)&zb[(size_t)t*64 + dq*4];     // 256B row/wave-token
        float4 wq = *(const float4*)&s_pw[kq*PW_STRIDE + t*4];    // 4 disjoint bank-quads
        float zv[4] = { zq.x, zq.y, zq.z, zq.w };
        float wv[4] = { wq.x, wq.y, wq.z, wq.w };
#pragma unroll
        for (int i = 0; i < 4; ++i)
#pragma unroll
            for (int j = 0; j < 4; ++j)
                acc[i][j] = fmaf(wv[i], zv[j], acc[i][j]);
    }
    __syncthreads();              // all pw reads done -> safe to alias buffer

    float* s_part = s_pw;         // [8 waves][16 k][64 d] = 32KB
#pragma unroll
    for (int i = 0; i < 4; ++i) {
        float4 v = make_float4(acc[i][0], acc[i][1], acc[i][2], acc[i][3]);
        *(float4*)&s_part[wid*1024 + (kq*4 + i)*64 + dq*4] = v;
    }
    __syncthreads();

    // ---------------- epilogue: reduce partials + beta_seq + final LN ----------------
    if (tid < 256) {
        int k  = tid >> 4;        // 0..15
        int dg = tid & 15;        // 0..15 (quad of d)
        float4 v = make_float4(0.f, 0.f, 0.f, 0.f);
#pragma unroll
        for (int w = 0; w < 8; ++w) {
            float4 p = *(const float4*)&s_part[w*1024 + k*64 + dg*4];
            v.x += p.x; v.y += p.y; v.z += p.z; v.w += p.w;
        }
        float4 bs = *(const float4*)&beta_seq[k*64 + dg*4];
        v.x += bs.x; v.y += bs.y; v.z += bs.z; v.w += bs.w;

        float s1 = (v.x + v.y) + (v.z + v.w);
        float s2 = dot4(v, v);
#pragma unroll
        for (int off = 1; off <= 8; off <<= 1) {   // reduce across the 16-lane group
            s1 += __shfl_xor(s1, off);
            s2 += __shfl_xor(s2, off);
        }
        float m   = s1 * (1.f / 64.f);
        float var = s2 * (1.f / 64.f) - m * m;
        float rs  = rs_nr(var + EPSF);
        float4 g4 = *(const float4*)&lng[4*64 + dg*4];
        float4 b4 = *(const float4*)&lnb[4*64 + dg*4];
        float4 o;
        o.x = fmaf((v.x - m) * rs, g4.x, b4.x);
        o.y = fmaf((v.y - m) * rs, g4.y, b4.y);
        o.z = fmaf((v.z - m) * rs, g4.z, b4.z);
        o.w = fmaf((v.w - m) * rs, g4.w, b4.w);
        *(float4*)&out[((size_t)b*16 + k)*64 + dg*4] = o;
    }
}

extern "C" void kernel_launch(void* const* d_in, const int* in_sizes, int n_in,
                              void* d_out, int out_size, void* d_ws, size_t ws_size,
                              hipStream_t stream) {
    const float* z        = (const float*)d_in[0];
    const float* proto    = (const float*)d_in[1];
    const float* alphas   = (const float*)d_in[2];
    const float* b_bias   = (const float*)d_in[3];
    const float* W        = (const float*)d_in[4];
    const float* Wb       = (const float*)d_in[5];
    const float* lng      = (const float*)d_in[6];
    const float* lnb      = (const float*)d_in[7];
    const float* beta_seq = (const float*)d_in[8];
    float* out = (float*)d_out;

    disent_encoder_kernel<<<dim3(512), dim3(512), 0, stream>>>(
        z, proto, alphas, b_bias, W, Wb, lng, lnb, beta_seq, out);
}